// Round 12
// baseline (552.452 us; speedup 1.0000x reference)
//
#include <hip/hip_runtime.h>
#include <hip/hip_cooperative_groups.h>
namespace cg = cooperative_groups;

#define HW 262144           // 512*512
#define CIN 16
#define OUTC 16

// ws layout (float offsets)
#define WS_PARTIALS 0       // [2048][6] floats
#define WS_COS      12288   // [8] floats
#define WS_WB_F     12296   // ushort region: [8][5 kb][2 hl][64 lane][8 j] bf16 = 40960 u16

typedef float  floatx4 __attribute__((ext_vector_type(4)));
typedef short  bf16x8  __attribute__((ext_vector_type(8)));

__device__ __forceinline__ ushort bf16_rne(float f) {
  unsigned u = __float_as_uint(f);
  unsigned r = (u + 0x7FFFu + ((u >> 16) & 1u)) >> 16;
  return (ushort)r;
}
__device__ __forceinline__ void bf16_split(float f, ushort& hi, ushort& lo) {
  hi = bf16_rne(f);
  float fh = __uint_as_float(((unsigned)hi) << 16);
  lo = bf16_rne(f - fh);
}

// ===========================================================================
// FUSED cooperative kernel: reduce -> stats -> rotw -> conv in one dispatch,
// so x (128 MB <= 256 MB L3) streamed by phase A is L3-resident for phase C.
// 1024 blocks x 256 thr = 4 blocks/CU x 256 CU (exactly resident).
// ===========================================================================
__global__ __launch_bounds__(256, 4) void k_fused(
    const float* __restrict__ x, const float* __restrict__ wfr,
    const float* __restrict__ wfi, const float* __restrict__ rot_w,
    const float* __restrict__ rot_b, const float* __restrict__ bn_g,
    const float* __restrict__ bn_b, float* __restrict__ out,
    float* __restrict__ ws) {
  __shared__ __align__(16) char smem[18 * 1096 * 2];   // 39456 B, phase-unioned

  float* partials = ws + WS_PARTIALS;
  ushort* wB = (ushort*)(ws + WS_WB_F);

  const int blk = blockIdx.x;   // 0..1023
  const int t = threadIdx.x;
  const int lane = t & 63;

  // ---------------- Phase A: streaming reduction (2 strips/block) ----------
  {
    float rw[3][16];
#pragma unroll
    for (int k = 0; k < 3; k++)
#pragma unroll
      for (int c = 0; c < 16; c++) rw[k][c] = rot_w[k * 16 + c];
    float rb[3];
#pragma unroll
    for (int k = 0; k < 3; k++) rb[k] = rot_b[k];

    float* redsh = (float*)smem;          // [4][6]
    const int wave = t >> 6;

    for (int ss = 0; ss < 2; ss++) {
      const int strip = blk * 2 + ss;     // 0..2047, same layout as k_reduce
      const int b = strip >> 8;
      const int s = strip & 255;
      const float* xb = x + (size_t)b * CIN * HW + s * 1024 + t * 4;

      float z[3][4];
#pragma unroll
      for (int k = 0; k < 3; k++)
#pragma unroll
        for (int j = 0; j < 4; j++) z[k][j] = 0.f;

#pragma unroll
      for (int c = 0; c < 16; c++) {
        float4 v = *reinterpret_cast<const float4*>(xb + (size_t)c * HW);
#pragma unroll
        for (int k = 0; k < 3; k++) {
          z[k][0] += rw[k][c] * v.x;
          z[k][1] += rw[k][c] * v.y;
          z[k][2] += rw[k][c] * v.z;
          z[k][3] += rw[k][c] * v.w;
        }
      }

      float vals[6];
#pragma unroll
      for (int k = 0; k < 3; k++) {
        float sz = 0.f, sz2 = 0.f;
#pragma unroll
        for (int j = 0; j < 4; j++) {
          float zz = z[k][j] + rb[k];
          sz += zz;
          sz2 += zz * zz;
        }
        vals[k] = sz;
        vals[3 + k] = sz2;
      }

#pragma unroll
      for (int v = 0; v < 6; v++) {
        float val = vals[v];
#pragma unroll
        for (int off = 32; off; off >>= 1) val += __shfl_down(val, off, 64);
        if (lane == 0) redsh[wave * 6 + v] = val;
      }
      __syncthreads();
      if (t < 6)
        partials[strip * 6 + t] =
            redsh[0 * 6 + t] + redsh[1 * 6 + t] + redsh[2 * 6 + t] + redsh[3 * 6 + t];
      __syncthreads();
    }
  }

  cg::this_grid().sync();

  // ---------------- Phase B: stats + rotw (blocks 0..7, block b = batch b) --
  if (blk < 8) {
    float* Msh = (float*)smem;        // [8][3]
    float* vsum = Msh + 24;           // [3]

    if (t < 24) {
      int b = t / 3, c = t - b * 3;
      float s = 0.f;
      for (int i = 0; i < 256; i++) s += partials[(b * 256 + i) * 6 + c];
      Msh[b * 3 + c] = s;
    }
    if (t >= 64) {
      int c = (t - 64) >> 6;
      int ln = t & 63;
      float s = 0.f;
      for (int i = ln; i < 2048; i += 64) s += partials[i * 6 + 3 + c];
#pragma unroll
      for (int off = 32; off; off >>= 1) s += __shfl_down(s, off, 64);
      if (ln == 0) vsum[c] = s;
    }
    __syncthreads();

    // every thread computes the (identical) angle for batch = blk
    const float invN = 1.0f / (8.0f * 262144.0f);
    const float invHW = 1.0f / 262144.0f;
    float angle = 0.f;
#pragma unroll
    for (int c = 0; c < 3; c++) {
      float tot = 0.f;
#pragma unroll
      for (int b = 0; b < 8; b++) tot += Msh[b * 3 + c];
      float mu = tot * invN;
      float var = vsum[c] * invN - mu * mu;
      float rs = rsqrtf(var + 1e-5f);
      angle += (Msh[blk * 3 + c] * invHW - mu) * rs * bn_g[c] + bn_b[c];
    }
    const float ct = cosf(tanhf(angle) * 0.7853981633974483f);

    // rotw for batch blk, thread handles (o = t&15, c = t>>4)
    const int o = t & 15;
    const int c = t >> 4;
    const float phi = ct * 2.0943951023931953f;
    float sp, cp;
    sincosf(phi, &sp, &cp);
    const float ur[3] = {1.f, cp, cp};
    const float ui[3] = {0.f, -sp, sp};
    const float wr3[3] = {1.f, -0.5f, -0.5f};
    const float wi3[3] = {0.f, 0.8660254037844386f, -0.8660254037844386f};

    float cr[3][3], ci[3][3];
#pragma unroll
    for (int k = 0; k < 3; k++)
#pragma unroll
      for (int m2 = 0; m2 < 3; m2++) {
        int e = (k * m2) % 3;
        cr[k][m2] = ur[k] * wr3[e] - ui[k] * wi3[e];
        ci[k][m2] = ur[k] * wi3[e] + ui[k] * wr3[e];
      }

    const float* Ar = wfr + (o * 16 + c) * 27;
    const float* Ai = wfi + (o * 16 + c) * 27;

    float outv[9];
#pragma unroll
    for (int i = 0; i < 9; i++) outv[i] = 0.f;

#pragma unroll
    for (int k1 = 0; k1 < 3; k1++) {
      float ar[9], ai[9];
#pragma unroll
      for (int i = 0; i < 9; i++) { ar[i] = Ar[k1 * 9 + i]; ai[i] = Ai[k1 * 9 + i]; }
      float hr[3][3], hi2[3][3];
#pragma unroll
      for (int k2 = 0; k2 < 3; k2++)
#pragma unroll
        for (int q = 0; q < 3; q++) {
          float sr = 0.f, si = 0.f;
#pragma unroll
          for (int k3 = 0; k3 < 3; k3++) {
            float xr = ar[k2 * 3 + k3], xi = ai[k2 * 3 + k3];
            sr += xr * cr[k3][q] - xi * ci[k3][q];
            si += xr * ci[k3][q] + xi * cr[k3][q];
          }
          hr[k2][q] = sr;
          hi2[k2][q] = si;
        }
      float drr = cr[k1][1], dii = ci[k1][1];
#pragma unroll
      for (int p = 0; p < 3; p++)
#pragma unroll
        for (int q = 0; q < 3; q++) {
          float sr = 0.f, si = 0.f;
#pragma unroll
          for (int k2 = 0; k2 < 3; k2++) {
            sr += hr[k2][q] * cr[k2][p] - hi2[k2][q] * ci[k2][p];
            si += hr[k2][q] * ci[k2][p] + hi2[k2][q] * cr[k2][p];
          }
          outv[p * 3 + q] += sr * drr - si * dii;
        }
    }

#pragma unroll
    for (int tap = 0; tap < 9; tap++) {
      float v = outv[tap] * (1.0f / 27.0f);
      int k = tap * 16 + c;
      int kb = k >> 5;
      int g = (k >> 3) & 3;
      int j = k & 7;
      int ln = g * 16 + o;
      ushort hi, lo;
      bf16_split(v, hi, lo);
      int idx = ((blk * 5 + kb) * 2) * 512 + ln * 8 + j;
      wB[idx] = hi;
      wB[idx + 512] = lo;
    }
#pragma unroll
    for (int u = 0; u < 2; u++) {
      int e = t * 2 + u;
      int hl = e >> 8;
      int rem = e & 255;
      int kk = 144 + (rem >> 4);
      int o2 = rem & 15;
      int g2 = (kk >> 3) & 3;
      int ln2 = g2 * 16 + o2;
      int j2 = kk & 7;
      wB[((blk * 5 + 4) * 2 + hl) * 512 + ln2 * 8 + j2] = 0;
    }
  }

  cg::this_grid().sync();

  // ---------------- Phase C: conv, 4 col-adjacent tiles per block ----------
  {
    ushort* xsb = (ushort*)smem;
    const int b = blk & 7;
    const ushort* wBb = wB + b * 5120;
    bf16x8 wh[5], wl[5];
#pragma unroll
    for (int kb = 0; kb < 5; kb++) {
      wh[kb] = *reinterpret_cast<const bf16x8*>(wBb + (kb * 2 + 0) * 512 + lane * 8);
      wl[kb] = *reinterpret_cast<const bf16x8*>(wBb + (kb * 2 + 1) * 512 + lane * 8);
    }

    const int m = lane & 15;
    const int g = lane >> 4;
    const int chalf = g & 1;
    const int tsel = g >> 1;
    int offh[5], offl[5];
#pragma unroll
    for (int kb = 0; kb < 5; kb++) {
      int tap = kb * 2 + tsel;
      if (tap > 8) tap = 8;
      int dy = tap / 3;
      int dx = tap - dy * 3;
      int mdx = m + dx;
      int swz = (mdx >> 1) & 3;
      offh[kb] = dy * 1096 + mdx * 32 + ((chalf ^ swz) << 3);
      offl[kb] = dy * 1096 + mdx * 32 + (((2 | chalf) ^ swz) << 3);
    }

    const float* xb = x + (size_t)b * CIN * HW;
    const int w = t >> 6;
    const int oo = lane & 15;
    const int quad = lane >> 4;

    for (int tt = 0; tt < 4; tt++) {
      const int rem0 = (blk >> 3) * 4 + tt;   // 0..511 within this batch
      const int row0 = (rem0 >> 4) * 16;
      const int col0 = (rem0 & 15) * 32;

      __syncthreads();   // previous tile's LDS reads complete

#pragma unroll
      for (int it = 0; it < 5; it++) {
        int p = it * 256 + t;
        if (p < 1224) {
          int row = p / 68;
          int rem2 = p - row * 68;
          int col = rem2 >> 1;
          int ch = rem2 & 1;
          int gr = row0 - 1 + row;
          int gc = col0 - 1 + col;
          bool ok = ((unsigned)gr < 512u) && ((unsigned)gc < 512u);
          const float* src = xb + (size_t)(ch * 8) * HW + gr * 512 + gc;
          bf16x8 hv, lv;
#pragma unroll
          for (int j = 0; j < 8; j++) {
            float v = ok ? src[(size_t)j * HW] : 0.f;
            ushort hi, lo;
            bf16_split(v, hi, lo);
            hv[j] = (short)hi;
            lv[j] = (short)lo;
          }
          int swz = (col >> 1) & 3;
          int base = row * 1096 + col * 32;
          *reinterpret_cast<bf16x8*>(&xsb[base + ((ch ^ swz) << 3)]) = hv;
          *reinterpret_cast<bf16x8*>(&xsb[base + (((2 | ch) ^ swz) << 3)]) = lv;
        }
      }
      __syncthreads();

#pragma unroll
      for (int s = 0; s < 8; s++) {
        int r = w * 4 + (s >> 1);
        int cg2 = s & 1;
        int base = r * 1096 + cg2 * 512;
        floatx4 acc = {0.f, 0.f, 0.f, 0.f};
#pragma unroll
        for (int kb = 0; kb < 5; kb++) {
          bf16x8 a_hi = *reinterpret_cast<const bf16x8*>(&xsb[base + offh[kb]]);
          bf16x8 a_lo = *reinterpret_cast<const bf16x8*>(&xsb[base + offl[kb]]);
          acc = __builtin_amdgcn_mfma_f32_16x16x32_bf16(a_hi, wh[kb], acc, 0, 0, 0);
          acc = __builtin_amdgcn_mfma_f32_16x16x32_bf16(a_hi, wl[kb], acc, 0, 0, 0);
          acc = __builtin_amdgcn_mfma_f32_16x16x32_bf16(a_lo, wh[kb], acc, 0, 0, 0);
        }
        float* dst = out + (size_t)(b * OUTC + oo) * HW +
                     (size_t)(row0 + r) * 512 + col0 + cg2 * 16 + quad * 4;
        // nontemporal: don't let out-writes evict x from L3
        __builtin_nontemporal_store(acc, reinterpret_cast<floatx4*>(dst));
      }
    }
  }
}

// ===========================================================================
// Fallback path: the measured-correct 4-kernel pipeline (R4/R6).
// ===========================================================================
__global__ __launch_bounds__(256) void k_reduce(const float* __restrict__ x,
                                                const float* __restrict__ rot_w,
                                                const float* __restrict__ rot_b,
                                                float* __restrict__ partials) {
  const int blk = blockIdx.x;
  const int b = blk >> 8;
  const int s = blk & 255;
  const int t = threadIdx.x;

  float rw[3][16];
#pragma unroll
  for (int k = 0; k < 3; k++)
#pragma unroll
    for (int c = 0; c < 16; c++) rw[k][c] = rot_w[k * 16 + c];
  float rb[3];
#pragma unroll
  for (int k = 0; k < 3; k++) rb[k] = rot_b[k];

  const float* xb = x + (size_t)b * CIN * HW + s * 1024 + t * 4;

  float z[3][4];
#pragma unroll
  for (int k = 0; k < 3; k++)
#pragma unroll
    for (int j = 0; j < 4; j++) z[k][j] = 0.f;

#pragma unroll
  for (int c = 0; c < 16; c++) {
    float4 v = *reinterpret_cast<const float4*>(xb + (size_t)c * HW);
#pragma unroll
    for (int k = 0; k < 3; k++) {
      z[k][0] += rw[k][c] * v.x;
      z[k][1] += rw[k][c] * v.y;
      z[k][2] += rw[k][c] * v.z;
      z[k][3] += rw[k][c] * v.w;
    }
  }

  float vals[6];
#pragma unroll
  for (int k = 0; k < 3; k++) {
    float sz = 0.f, sz2 = 0.f;
#pragma unroll
    for (int j = 0; j < 4; j++) {
      float zz = z[k][j] + rb[k];
      sz += zz;
      sz2 += zz * zz;
    }
    vals[k] = sz;
    vals[3 + k] = sz2;
  }

  __shared__ float redsh[4][6];
  const int wave = t >> 6, lane = t & 63;
#pragma unroll
  for (int v = 0; v < 6; v++) {
    float val = vals[v];
#pragma unroll
    for (int off = 32; off; off >>= 1) val += __shfl_down(val, off, 64);
    if (lane == 0) redsh[wave][v] = val;
  }
  __syncthreads();
  if (t < 6)
    partials[blk * 6 + t] = redsh[0][t] + redsh[1][t] + redsh[2][t] + redsh[3][t];
}

__global__ __launch_bounds__(256) void k_stats(const float* __restrict__ partials,
                                               const float* __restrict__ bn_gamma,
                                               const float* __restrict__ bn_beta,
                                               float* __restrict__ cos_theta) {
  __shared__ float Msh[8][3];
  __shared__ float varsum[3];
  const int t = threadIdx.x;

  if (t < 24) {
    int b = t / 3, c = t - b * 3;
    float s = 0.f;
    for (int i = 0; i < 256; i++) s += partials[(b * 256 + i) * 6 + c];
    Msh[b][c] = s;
  }
  if (t >= 64) {
    int c = (t - 64) >> 6;
    int lane = t & 63;
    float s = 0.f;
    for (int i = lane; i < 2048; i += 64) s += partials[i * 6 + 3 + c];
#pragma unroll
    for (int off = 32; off; off >>= 1) s += __shfl_down(s, off, 64);
    if (lane == 0) varsum[c] = s;
  }
  __syncthreads();

  if (t < 8) {
    const float invN = 1.0f / (8.0f * 262144.0f);
    const float invHW = 1.0f / 262144.0f;
    float angle = 0.f;
#pragma unroll
    for (int c = 0; c < 3; c++) {
      float tot = 0.f;
#pragma unroll
      for (int b = 0; b < 8; b++) tot += Msh[b][c];
      float mu = tot * invN;
      float var = varsum[c] * invN - mu * mu;
      float rs = rsqrtf(var + 1e-5f);
      angle += (Msh[t][c] * invHW - mu) * rs * bn_gamma[c] + bn_beta[c];
    }
    float a = tanhf(angle) * 0.7853981633974483f;
    cos_theta[t] = cosf(a);
  }
}

__global__ __launch_bounds__(256) void k_rotw(const float* __restrict__ wfr,
                                              const float* __restrict__ wfi,
                                              const float* __restrict__ cos_theta,
                                              ushort* __restrict__ wB) {
  const int b = blockIdx.x;
  const int t = threadIdx.x;
  const int o = t & 15;
  const int c = t >> 4;

  const float ct = cos_theta[b];
  const float phi = ct * 2.0943951023931953f;
  float sp, cp;
  sincosf(phi, &sp, &cp);
  const float ur[3] = {1.f, cp, cp};
  const float ui[3] = {0.f, -sp, sp};
  const float wr3[3] = {1.f, -0.5f, -0.5f};
  const float wi3[3] = {0.f, 0.8660254037844386f, -0.8660254037844386f};

  float cr[3][3], ci[3][3];
#pragma unroll
  for (int k = 0; k < 3; k++)
#pragma unroll
    for (int m = 0; m < 3; m++) {
      int e = (k * m) % 3;
      cr[k][m] = ur[k] * wr3[e] - ui[k] * wi3[e];
      ci[k][m] = ur[k] * wi3[e] + ui[k] * wr3[e];
    }

  const float* Ar = wfr + (o * 16 + c) * 27;
  const float* Ai = wfi + (o * 16 + c) * 27;

  float outv[9];
#pragma unroll
  for (int i = 0; i < 9; i++) outv[i] = 0.f;

#pragma unroll
  for (int k1 = 0; k1 < 3; k1++) {
    float ar[9], ai[9];
#pragma unroll
    for (int i = 0; i < 9; i++) { ar[i] = Ar[k1 * 9 + i]; ai[i] = Ai[k1 * 9 + i]; }
    float hr[3][3], hi2[3][3];
#pragma unroll
    for (int k2 = 0; k2 < 3; k2++)
#pragma unroll
      for (int q = 0; q < 3; q++) {
        float sr = 0.f, si = 0.f;
#pragma unroll
        for (int k3 = 0; k3 < 3; k3++) {
          float xr = ar[k2 * 3 + k3], xi = ai[k2 * 3 + k3];
          sr += xr * cr[k3][q] - xi * ci[k3][q];
          si += xr * ci[k3][q] + xi * cr[k3][q];
        }
        hr[k2][q] = sr;
        hi2[k2][q] = si;
      }
    float drr = cr[k1][1], dii = ci[k1][1];
#pragma unroll
    for (int p = 0; p < 3; p++)
#pragma unroll
      for (int q = 0; q < 3; q++) {
        float sr = 0.f, si = 0.f;
#pragma unroll
        for (int k2 = 0; k2 < 3; k2++) {
          sr += hr[k2][q] * cr[k2][p] - hi2[k2][q] * ci[k2][p];
          si += hr[k2][q] * ci[k2][p] + hi2[k2][q] * cr[k2][p];
        }
        outv[p * 3 + q] += sr * drr - si * dii;
      }
  }

#pragma unroll
  for (int tap = 0; tap < 9; tap++) {
    float v = outv[tap] * (1.0f / 27.0f);
    int k = tap * 16 + c;
    int kb = k >> 5;
    int g = (k >> 3) & 3;
    int j = k & 7;
    int ln = g * 16 + o;
    ushort hi, lo;
    bf16_split(v, hi, lo);
    int idx = ((b * 5 + kb) * 2) * 512 + ln * 8 + j;
    wB[idx] = hi;
    wB[idx + 512] = lo;
  }

#pragma unroll
  for (int u = 0; u < 2; u++) {
    int e = t * 2 + u;
    int hl = e >> 8;
    int rem = e & 255;
    int kk = 144 + (rem >> 4);
    int o2 = rem & 15;
    int g2 = (kk >> 3) & 3;
    int ln2 = g2 * 16 + o2;
    int j2 = kk & 7;
    wB[((b * 5 + 4) * 2 + hl) * 512 + ln2 * 8 + j2] = 0;
  }
}

__global__ __launch_bounds__(256, 4) void k_conv(const float* __restrict__ x,
                                                 const ushort* __restrict__ wB,
                                                 float* __restrict__ out) {
  __shared__ ushort xsb[18 * 1096];

  const int id = blockIdx.x;
  const int nid = (id & 7) * 512 + (id >> 3);
  const int b = nid >> 9;
  const int rem0 = nid & 511;
  const int row0 = (rem0 >> 4) * 16;
  const int col0 = (rem0 & 15) * 32;
  const int t = threadIdx.x;
  const int lane = t & 63;

  const ushort* wBb = wB + b * 5120;
  bf16x8 wh[5], wl[5];
#pragma unroll
  for (int kb = 0; kb < 5; kb++) {
    wh[kb] = *reinterpret_cast<const bf16x8*>(wBb + (kb * 2 + 0) * 512 + lane * 8);
    wl[kb] = *reinterpret_cast<const bf16x8*>(wBb + (kb * 2 + 1) * 512 + lane * 8);
  }

  const float* xb = x + (size_t)b * CIN * HW;
#pragma unroll
  for (int it = 0; it < 5; it++) {
    int p = it * 256 + t;
    if (p < 1224) {
      int row = p / 68;
      int rem2 = p - row * 68;
      int col = rem2 >> 1;
      int chalf = rem2 & 1;
      int gr = row0 - 1 + row;
      int gc = col0 - 1 + col;
      bool ok = ((unsigned)gr < 512u) && ((unsigned)gc < 512u);
      const float* src = xb + (size_t)(chalf * 8) * HW + gr * 512 + gc;
      bf16x8 hv, lv;
#pragma unroll
      for (int j = 0; j < 8; j++) {
        float v = ok ? src[(size_t)j * HW] : 0.f;
        ushort hi, lo;
        bf16_split(v, hi, lo);
        hv[j] = (short)hi;
        lv[j] = (short)lo;
      }
      int swz = (col >> 1) & 3;
      int base = row * 1096 + col * 32;
      *reinterpret_cast<bf16x8*>(&xsb[base + ((chalf ^ swz) << 3)]) = hv;
      *reinterpret_cast<bf16x8*>(&xsb[base + (((2 | chalf) ^ swz) << 3)]) = lv;
    }
  }

  const int m = lane & 15;
  const int g = lane >> 4;
  const int chalf = g & 1;
  const int tsel = g >> 1;
  int offh[5], offl[5];
#pragma unroll
  for (int kb = 0; kb < 5; kb++) {
    int tap = kb * 2 + tsel;
    if (tap > 8) tap = 8;
    int dy = tap / 3;
    int dx = tap - dy * 3;
    int mdx = m + dx;
    int swz = (mdx >> 1) & 3;
    offh[kb] = dy * 1096 + mdx * 32 + ((chalf ^ swz) << 3);
    offl[kb] = dy * 1096 + mdx * 32 + (((2 | chalf) ^ swz) << 3);
  }

  __syncthreads();

  const int w = t >> 6;
  const int oo = lane & 15;
  const int quad = lane >> 4;
#pragma unroll
  for (int s = 0; s < 8; s++) {
    int r = w * 4 + (s >> 1);
    int cg = s & 1;
    int base = r * 1096 + cg * 512;
    floatx4 acc = {0.f, 0.f, 0.f, 0.f};
#pragma unroll
    for (int kb = 0; kb < 5; kb++) {
      bf16x8 a_hi = *reinterpret_cast<const bf16x8*>(&xsb[base + offh[kb]]);
      bf16x8 a_lo = *reinterpret_cast<const bf16x8*>(&xsb[base + offl[kb]]);
      acc = __builtin_amdgcn_mfma_f32_16x16x32_bf16(a_hi, wh[kb], acc, 0, 0, 0);
      acc = __builtin_amdgcn_mfma_f32_16x16x32_bf16(a_hi, wl[kb], acc, 0, 0, 0);
      acc = __builtin_amdgcn_mfma_f32_16x16x32_bf16(a_lo, wh[kb], acc, 0, 0, 0);
    }
    float* dst = out + (size_t)(b * OUTC + oo) * HW + (size_t)(row0 + r) * 512 +
                 col0 + cg * 16 + quad * 4;
    *reinterpret_cast<float4*>(dst) = make_float4(acc[0], acc[1], acc[2], acc[3]);
  }
}

extern "C" void kernel_launch(void* const* d_in, const int* in_sizes, int n_in,
                              void* d_out, int out_size, void* d_ws, size_t ws_size,
                              hipStream_t stream) {
  const float* x      = (const float*)d_in[0];
  const float* wfr    = (const float*)d_in[1];
  const float* wfi    = (const float*)d_in[2];
  const float* rot_w  = (const float*)d_in[3];
  const float* rot_b  = (const float*)d_in[4];
  const float* bn_g   = (const float*)d_in[5];
  const float* bn_b   = (const float*)d_in[6];
  float* out = (float*)d_out;
  float* ws  = (float*)d_ws;

  void* args[] = {(void*)&x, (void*)&wfr, (void*)&wfi, (void*)&rot_w,
                  (void*)&rot_b, (void*)&bn_g, (void*)&bn_b, (void*)&out,
                  (void*)&ws};
  hipError_t err = hipLaunchCooperativeKernel((void*)k_fused, dim3(1024),
                                              dim3(256), args, 0, stream);
  if (err != hipSuccess) {
    // fallback: measured-correct 4-kernel pipeline
    float* partials = ws + WS_PARTIALS;
    float* cosw     = ws + WS_COS;
    ushort* wB      = (ushort*)(ws + WS_WB_F);
    k_reduce<<<2048, 256, 0, stream>>>(x, rot_w, rot_b, partials);
    k_stats<<<1, 256, 0, stream>>>(partials, bn_g, bn_b, cosw);
    k_rotw<<<8, 256, 0, stream>>>(wfr, wfi, cosw, wB);
    k_conv<<<4096, 256, 0, stream>>>(x, wB, out);
  }
}

// Round 13
// 295.041 us; speedup vs baseline: 1.8725x; 1.8725x over previous
//
#include <hip/hip_runtime.h>

#define HW 262144           // 512*512
#define CIN 16
#define OUTC 16

// ws layout (float offsets)
#define WS_PARTIALS 0       // [2048][6] floats
#define WS_WB_F     12296   // ushort region: [8][5 kb][2 hl][64 lane][8 j] bf16 = 40960 u16

typedef float  floatx4 __attribute__((ext_vector_type(4)));
typedef short  bf16x8  __attribute__((ext_vector_type(8)));

__device__ __forceinline__ ushort bf16_rne(float f) {
  unsigned u = __float_as_uint(f);
  unsigned r = (u + 0x7FFFu + ((u >> 16) & 1u)) >> 16;
  return (ushort)r;
}
__device__ __forceinline__ void bf16_split(float f, ushort& hi, ushort& lo) {
  hi = bf16_rne(f);
  float fh = __uint_as_float(((unsigned)hi) << 16);
  lo = bf16_rne(f - fh);
}

// ---------------------------------------------------------------------------
// Kernel 1: streaming reduction over x (measured-correct, unchanged).
// ---------------------------------------------------------------------------
__global__ __launch_bounds__(256) void k_reduce(const float* __restrict__ x,
                                                const float* __restrict__ rot_w,
                                                const float* __restrict__ rot_b,
                                                float* __restrict__ partials) {
  const int blk = blockIdx.x;       // 0..2047
  const int b = blk >> 8;
  const int s = blk & 255;
  const int t = threadIdx.x;

  float rw[3][16];
#pragma unroll
  for (int k = 0; k < 3; k++)
#pragma unroll
    for (int c = 0; c < 16; c++) rw[k][c] = rot_w[k * 16 + c];
  float rb[3];
#pragma unroll
  for (int k = 0; k < 3; k++) rb[k] = rot_b[k];

  const float* xb = x + (size_t)b * CIN * HW + s * 1024 + t * 4;

  float z[3][4];
#pragma unroll
  for (int k = 0; k < 3; k++)
#pragma unroll
    for (int j = 0; j < 4; j++) z[k][j] = 0.f;

#pragma unroll
  for (int c = 0; c < 16; c++) {
    float4 v = *reinterpret_cast<const float4*>(xb + (size_t)c * HW);
#pragma unroll
    for (int k = 0; k < 3; k++) {
      z[k][0] += rw[k][c] * v.x;
      z[k][1] += rw[k][c] * v.y;
      z[k][2] += rw[k][c] * v.z;
      z[k][3] += rw[k][c] * v.w;
    }
  }

  float vals[6];
#pragma unroll
  for (int k = 0; k < 3; k++) {
    float sz = 0.f, sz2 = 0.f;
#pragma unroll
    for (int j = 0; j < 4; j++) {
      float zz = z[k][j] + rb[k];
      sz += zz;
      sz2 += zz * zz;
    }
    vals[k] = sz;
    vals[3 + k] = sz2;
  }

  __shared__ float redsh[4][6];
  const int wave = t >> 6, lane = t & 63;
#pragma unroll
  for (int v = 0; v < 6; v++) {
    float val = vals[v];
#pragma unroll
    for (int off = 32; off; off >>= 1) val += __shfl_down(val, off, 64);
    if (lane == 0) redsh[wave][v] = val;
  }
  __syncthreads();
  if (t < 6)
    partials[blk * 6 + t] = redsh[0][t] + redsh[1][t] + redsh[2][t] + redsh[3][t];
}

// ---------------------------------------------------------------------------
// Kernel 2: merged stats+rotw (8 blocks; block b = batch b). Body is the
// hardware-validated Phase B of the R12 fused kernel: fold partials -> BN
// stats -> angle for THIS batch -> phase-rotated DFT weights in the per-lane
// MFMA B-fragment layout. Saves one dispatch + the cos_theta round-trip.
// ---------------------------------------------------------------------------
__global__ __launch_bounds__(256) void k_statrotw(const float* __restrict__ partials,
                                                  const float* __restrict__ bn_g,
                                                  const float* __restrict__ bn_b,
                                                  const float* __restrict__ wfr,
                                                  const float* __restrict__ wfi,
                                                  ushort* __restrict__ wB) {
  __shared__ float Msh[24];    // [8][3]
  __shared__ float vsum[3];
  const int blk = blockIdx.x;  // batch
  const int t = threadIdx.x;

  if (t < 24) {
    int b = t / 3, c = t - b * 3;
    float s = 0.f;
    for (int i = 0; i < 256; i++) s += partials[(b * 256 + i) * 6 + c];
    Msh[b * 3 + c] = s;
  }
  if (t >= 64) {
    int c = (t - 64) >> 6;
    int ln = t & 63;
    float s = 0.f;
    for (int i = ln; i < 2048; i += 64) s += partials[i * 6 + 3 + c];
#pragma unroll
    for (int off = 32; off; off >>= 1) s += __shfl_down(s, off, 64);
    if (ln == 0) vsum[c] = s;
  }
  __syncthreads();

  const float invN = 1.0f / (8.0f * 262144.0f);
  const float invHW = 1.0f / 262144.0f;
  float angle = 0.f;
#pragma unroll
  for (int c = 0; c < 3; c++) {
    float tot = 0.f;
#pragma unroll
    for (int b = 0; b < 8; b++) tot += Msh[b * 3 + c];
    float mu = tot * invN;
    float var = vsum[c] * invN - mu * mu;
    float rs = rsqrtf(var + 1e-5f);
    angle += (Msh[blk * 3 + c] * invHW - mu) * rs * bn_g[c] + bn_b[c];
  }
  const float ct = cosf(tanhf(angle) * 0.7853981633974483f);

  const int o = t & 15;
  const int c = t >> 4;
  const float phi = ct * 2.0943951023931953f;   // 2*pi/3 * ct
  float sp, cp;
  sincosf(phi, &sp, &cp);
  const float ur[3] = {1.f, cp, cp};
  const float ui[3] = {0.f, -sp, sp};
  const float wr3[3] = {1.f, -0.5f, -0.5f};
  const float wi3[3] = {0.f, 0.8660254037844386f, -0.8660254037844386f};

  float cr[3][3], ci[3][3];
#pragma unroll
  for (int k = 0; k < 3; k++)
#pragma unroll
    for (int m2 = 0; m2 < 3; m2++) {
      int e = (k * m2) % 3;
      cr[k][m2] = ur[k] * wr3[e] - ui[k] * wi3[e];
      ci[k][m2] = ur[k] * wi3[e] + ui[k] * wr3[e];
    }

  const float* Ar = wfr + (o * 16 + c) * 27;
  const float* Ai = wfi + (o * 16 + c) * 27;

  float outv[9];
#pragma unroll
  for (int i = 0; i < 9; i++) outv[i] = 0.f;

#pragma unroll
  for (int k1 = 0; k1 < 3; k1++) {
    float ar[9], ai[9];
#pragma unroll
    for (int i = 0; i < 9; i++) { ar[i] = Ar[k1 * 9 + i]; ai[i] = Ai[k1 * 9 + i]; }
    float hr[3][3], hi2[3][3];
#pragma unroll
    for (int k2 = 0; k2 < 3; k2++)
#pragma unroll
      for (int q = 0; q < 3; q++) {
        float sr = 0.f, si = 0.f;
#pragma unroll
        for (int k3 = 0; k3 < 3; k3++) {
          float xr = ar[k2 * 3 + k3], xi = ai[k2 * 3 + k3];
          sr += xr * cr[k3][q] - xi * ci[k3][q];
          si += xr * ci[k3][q] + xi * cr[k3][q];
        }
        hr[k2][q] = sr;
        hi2[k2][q] = si;
      }
    float drr = cr[k1][1], dii = ci[k1][1];
#pragma unroll
    for (int p = 0; p < 3; p++)
#pragma unroll
      for (int q = 0; q < 3; q++) {
        float sr = 0.f, si = 0.f;
#pragma unroll
        for (int k2 = 0; k2 < 3; k2++) {
          sr += hr[k2][q] * cr[k2][p] - hi2[k2][q] * ci[k2][p];
          si += hr[k2][q] * ci[k2][p] + hi2[k2][q] * cr[k2][p];
        }
        outv[p * 3 + q] += sr * drr - si * dii;
      }
  }

#pragma unroll
  for (int tap = 0; tap < 9; tap++) {
    float v = outv[tap] * (1.0f / 27.0f);
    int k = tap * 16 + c;
    int kb = k >> 5;
    int g = (k >> 3) & 3;
    int j = k & 7;
    int ln = g * 16 + o;
    ushort hi, lo;
    bf16_split(v, hi, lo);
    int idx = ((blk * 5 + kb) * 2) * 512 + ln * 8 + j;
    wB[idx] = hi;         // hl = 0
    wB[idx + 512] = lo;   // hl = 1
  }

  // zero-pad k in [144,160), both hl
#pragma unroll
  for (int u = 0; u < 2; u++) {
    int e = t * 2 + u;
    int hl = e >> 8;
    int rem = e & 255;
    int kk = 144 + (rem >> 4);
    int o2 = rem & 15;
    int g2 = (kk >> 3) & 3;
    int ln2 = g2 * 16 + o2;
    int j2 = kk & 7;
    wB[((blk * 5 + 4) * 2 + hl) * 512 + ln2 * 8 + j2] = 0;
  }
}

// ---------------------------------------------------------------------------
// Kernel 3: implicit-GEMM conv via mfma_f32_16x16x32_bf16, bf16x3 split.
// Measured-correct R6 version, unchanged: register-transpose staging
// (8 scalar loads -> 2x ds_write_b128) + XCD-aware 1D grid swizzle.
// ---------------------------------------------------------------------------
__global__ __launch_bounds__(256, 4) void k_conv(const float* __restrict__ x,
                                                 const ushort* __restrict__ wB,
                                                 float* __restrict__ out) {
  __shared__ ushort xsb[18 * 1096];   // 39456 B

  const int id = blockIdx.x;
  const int nid = (id & 7) * 512 + (id >> 3);   // XCD swizzle (4096 % 8 == 0)
  const int b = nid >> 9;
  const int rem0 = nid & 511;
  const int row0 = (rem0 >> 4) * 16;
  const int col0 = (rem0 & 15) * 32;
  const int t = threadIdx.x;
  const int lane = t & 63;

  const ushort* wBb = wB + b * 5120;
  bf16x8 wh[5], wl[5];
#pragma unroll
  for (int kb = 0; kb < 5; kb++) {
    wh[kb] = *reinterpret_cast<const bf16x8*>(wBb + (kb * 2 + 0) * 512 + lane * 8);
    wl[kb] = *reinterpret_cast<const bf16x8*>(wBb + (kb * 2 + 1) * 512 + lane * 8);
  }

  const float* xb = x + (size_t)b * CIN * HW;
#pragma unroll
  for (int it = 0; it < 5; it++) {
    int p = it * 256 + t;                 // pair index over 18r * 34c * 2chalf
    if (p < 1224) {
      int row = p / 68;
      int rem2 = p - row * 68;
      int col = rem2 >> 1;
      int chalf = rem2 & 1;
      int gr = row0 - 1 + row;
      int gc = col0 - 1 + col;
      bool ok = ((unsigned)gr < 512u) && ((unsigned)gc < 512u);
      const float* src = xb + (size_t)(chalf * 8) * HW + gr * 512 + gc;
      bf16x8 hv, lv;
#pragma unroll
      for (int j = 0; j < 8; j++) {
        float v = ok ? src[(size_t)j * HW] : 0.f;
        ushort hi, lo;
        bf16_split(v, hi, lo);
        hv[j] = (short)hi;
        lv[j] = (short)lo;
      }
      int swz = (col >> 1) & 3;
      int base = row * 1096 + col * 32;
      *reinterpret_cast<bf16x8*>(&xsb[base + ((chalf ^ swz) << 3)]) = hv;
      *reinterpret_cast<bf16x8*>(&xsb[base + (((2 | chalf) ^ swz) << 3)]) = lv;
    }
  }

  const int m = lane & 15;
  const int g = lane >> 4;
  const int chalf = g & 1;
  const int tsel = g >> 1;
  int offh[5], offl[5];
#pragma unroll
  for (int kb = 0; kb < 5; kb++) {
    int tap = kb * 2 + tsel;
    if (tap > 8) tap = 8;        // pad reads real addrs; weights are zero
    int dy = tap / 3;
    int dx = tap - dy * 3;
    int mdx = m + dx;
    int swz = (mdx >> 1) & 3;
    offh[kb] = dy * 1096 + mdx * 32 + ((chalf ^ swz) << 3);
    offl[kb] = dy * 1096 + mdx * 32 + (((2 | chalf) ^ swz) << 3);
  }

  __syncthreads();

  const int w = t >> 6;
  const int oo = lane & 15;
  const int quad = lane >> 4;
#pragma unroll
  for (int s = 0; s < 8; s++) {
    int r = w * 4 + (s >> 1);
    int cg = s & 1;
    int base = r * 1096 + cg * 512;
    floatx4 acc = {0.f, 0.f, 0.f, 0.f};
#pragma unroll
    for (int kb = 0; kb < 5; kb++) {
      bf16x8 a_hi = *reinterpret_cast<const bf16x8*>(&xsb[base + offh[kb]]);
      bf16x8 a_lo = *reinterpret_cast<const bf16x8*>(&xsb[base + offl[kb]]);
      acc = __builtin_amdgcn_mfma_f32_16x16x32_bf16(a_hi, wh[kb], acc, 0, 0, 0);
      acc = __builtin_amdgcn_mfma_f32_16x16x32_bf16(a_hi, wl[kb], acc, 0, 0, 0);
      acc = __builtin_amdgcn_mfma_f32_16x16x32_bf16(a_lo, wh[kb], acc, 0, 0, 0);
    }
    // C/D: n(o) = lane&15, m(pos) = (lane>>4)*4 + reg
    float* dst = out + (size_t)(b * OUTC + oo) * HW + (size_t)(row0 + r) * 512 +
                 col0 + cg * 16 + quad * 4;
    *reinterpret_cast<float4*>(dst) = make_float4(acc[0], acc[1], acc[2], acc[3]);
  }
}

extern "C" void kernel_launch(void* const* d_in, const int* in_sizes, int n_in,
                              void* d_out, int out_size, void* d_ws, size_t ws_size,
                              hipStream_t stream) {
  const float* x      = (const float*)d_in[0];
  const float* wfr    = (const float*)d_in[1];
  const float* wfi    = (const float*)d_in[2];
  const float* rot_w  = (const float*)d_in[3];
  const float* rot_b  = (const float*)d_in[4];
  const float* bn_g   = (const float*)d_in[5];
  const float* bn_b   = (const float*)d_in[6];
  float* out = (float*)d_out;
  float* ws  = (float*)d_ws;

  float* partials = ws + WS_PARTIALS;
  ushort* wB      = (ushort*)(ws + WS_WB_F);

  k_reduce<<<2048, 256, 0, stream>>>(x, rot_w, rot_b, partials);
  k_statrotw<<<8, 256, 0, stream>>>(partials, bn_g, bn_b, wfr, wfi, wB);
  k_conv<<<4096, 256, 0, stream>>>(x, wB, out);
}